// Round 2
// baseline (465.994 us; speedup 1.0000x reference)
//
#include <hip/hip_runtime.h>
#include <stdint.h>

#define N  256
#define N2 (N * N)        // 65536
#define N3 (N * N * N)    // 16777216

// reflect index (jnp.pad mode='reflect'): -1 -> 1, 256 -> 254
__device__ __forceinline__ int refl(int t) {
    t = (t < 0) ? -t : t;
    return (t > N - 1) ? (2 * (N - 1) - t) : t;
}

// ---------------------------------------------------------------------------
// K1: fused Gaussian(3^3, sigma=1, reflect pad) -> Sobel(gx,gy,gz) -> |grad|
// Composite separable 5x5x5 stencils, computed fully in double so that any
// accumulation order matches a float64 reference to ~1e-15 relative.
//   gx = (A_d ⊗ B_h ⊗ D_w) * x / S
//   gy = (A_d ⊗ D_h ⊗ B_w) * x / S
//   gz = (D_d ⊗ A_h ⊗ A_w) * x / S
// where e = [e1,1,e1] (e1=exp(-1/2)), A = [1,1,1]*e, B = [1,2,1]*e,
// D = [-1,0,1]*e (1D correlations), S = (1+2*e1)^3.
// Border (any coord 0 or 255) is the zero pad of mag.
// ---------------------------------------------------------------------------
__global__ __launch_bounds__(256) void mag_kernel(const float* __restrict__ x,
                                                  double* __restrict__ mag) {
    const int w = threadIdx.x;
    const int h = blockIdx.y;
    const int d = blockIdx.z;
    const size_t idx = (size_t)d * N2 + (size_t)h * N + w;

    if (d == 0 || d == N - 1 || h == 0 || h == N - 1 || w == 0 || w == N - 1) {
        mag[idx] = 0.0;
        return;
    }

    const double e1 = 0.6065306597126334236038;  // exp(-0.5)
    const double A[5]  = { e1, 1.0 + e1, 1.0 + 2.0 * e1, 1.0 + e1, e1 };
    const double B[5]  = { e1, 1.0 + 2.0 * e1, 2.0 + 2.0 * e1, 1.0 + 2.0 * e1, e1 };
    const double Dk[5] = { -e1, -1.0, 0.0, 1.0, e1 };
    const double s1 = 1.0 + 2.0 * e1;
    const double invS = 1.0 / (s1 * s1 * s1);

    // per-axis source indices (reflect only bites at w,h,d == 1 or 254)
    int wi[5], hi5[5], di[5];
#pragma unroll
    for (int c = 0; c < 5; ++c) {
        wi[c]  = refl(w - 2 + c);
        hi5[c] = refl(h - 2 + c);
        di[c]  = refl(d - 2 + c);
    }

    double gx = 0.0, gy = 0.0, gz = 0.0;
#pragma unroll
    for (int a = 0; a < 5; ++a) {
        const float* pz = x + (size_t)di[a] * N2;
#pragma unroll
        for (int b = 0; b < 5; ++b) {
            const float* py = pz + (size_t)hi5[b] * N;
            double rA = 0.0, rB = 0.0, rD = 0.0;
#pragma unroll
            for (int c = 0; c < 5; ++c) {
                const double v = (double)py[wi[c]];
                rA += A[c] * v;
                rB += B[c] * v;
                rD += Dk[c] * v;
            }
            gx += A[a]  * B[b]  * rD;
            gy += A[a]  * Dk[b] * rB;
            gz += Dk[a] * A[b]  * rA;
        }
    }
    gx *= invS; gy *= invS; gz *= invS;
    mag[idx] = sqrt(gx * gx + gy * gy + gz * gz);
}

// ---------------------------------------------------------------------------
// K2: NMS (strictly greater than all 8 upper (d-1) diagonal/edge neighbors)
// then double threshold. flags: 2 = strong, 1 = weak, 0 = none.
// ---------------------------------------------------------------------------
__global__ __launch_bounds__(256) void nms_kernel(const double* __restrict__ mag,
                                                  uint8_t* __restrict__ flags) {
    const int w = threadIdx.x;
    const int h = blockIdx.y;
    const int d = blockIdx.z;
    const size_t idx = (size_t)d * N2 + (size_t)h * N + w;

    uint8_t f = 0;
    if (d > 0 && d < N - 1 && h > 0 && h < N - 1 && w > 0 && w < N - 1) {
        const double m0 = mag[idx];
        const double* p = mag + (size_t)(d - 1) * N2 + (size_t)h * N + w;
        const bool keep =
            (m0 > p[-N - 1]) && (m0 > p[-N]) && (m0 > p[-N + 1]) &&
            (m0 > p[-1])     &&                  (m0 > p[1])     &&
            (m0 > p[N - 1])  && (m0 > p[N])  && (m0 > p[N + 1]);
        if (keep) f = (m0 > 0.2) ? 2 : ((m0 > 0.1) ? 1 : 0);
    }
    flags[idx] = f;
}

// ---------------------------------------------------------------------------
// K3: single-pass hysteresis: strong, or weak with a 6-connected strong nbr.
// Output is int32 0/1 (harness reads d_out as np.int32 for int8 reference).
// ---------------------------------------------------------------------------
__global__ __launch_bounds__(256) void hyst_kernel(const uint8_t* __restrict__ flags,
                                                   int* __restrict__ out) {
    const int w = threadIdx.x;
    const int h = blockIdx.y;
    const int d = blockIdx.z;
    const size_t idx = (size_t)d * N2 + (size_t)h * N + w;

    const uint8_t f = flags[idx];
    int r = 0;
    if (f == 2) {
        r = 1;
    } else if (f == 1) {  // weak implies interior, so all 6 nbrs in-bounds
        if (flags[idx - N2] == 2 || flags[idx + N2] == 2 ||
            flags[idx - N]  == 2 || flags[idx + N]  == 2 ||
            flags[idx - 1]  == 2 || flags[idx + 1]  == 2)
            r = 1;
    }
    out[idx] = r;
}

extern "C" void kernel_launch(void* const* d_in, const int* in_sizes, int n_in,
                              void* d_out, int out_size, void* d_ws, size_t ws_size,
                              hipStream_t stream) {
    const float* x = (const float*)d_in[0];
    int* out = (int*)d_out;

    // ws layout: [0, 128MiB) f64 mag; [128MiB, 144MiB) u8 flags
    double* mag = (double*)d_ws;
    uint8_t* flags = (uint8_t*)d_ws + (size_t)N3 * sizeof(double);

    dim3 block(N, 1, 1);
    dim3 grid(1, N, N);
    mag_kernel<<<grid, block, 0, stream>>>(x, mag);
    nms_kernel<<<grid, block, 0, stream>>>(mag, flags);
    hyst_kernel<<<grid, block, 0, stream>>>(flags, out);
}

// Round 3
// 251.073 us; speedup vs baseline: 1.8560x; 1.8560x over previous
//
#include <hip/hip_runtime.h>
#include <stdint.h>

#define N  256
#define N2 (N * N)        // 65536
#define N3 (N * N * N)    // 16777216

#define EPS 1e-4f         // decision-uncertainty margin (>> worst-case f32 error ~1e-5)
#define CAP (4u << 20)    // marked-voxel list capacity (16 MiB of u32)

// reflect index (jnp.pad mode='reflect'): -1 -> 1, 256 -> 254
__device__ __forceinline__ int refl(int t) {
    t = (t < 0) ? -t : t;
    return (t > N - 1) ? (2 * (N - 1) - t) : t;
}

// ---------------------------------------------------------------------------
// Exact f64 mag — byte-identical math to the round-2 verified kernel.
// Border (any coord 0 or N-1) is the zero pad of mag.
// ---------------------------------------------------------------------------
__device__ double mag_f64(const float* __restrict__ x, int d, int h, int w) {
    if (d == 0 || d == N - 1 || h == 0 || h == N - 1 || w == 0 || w == N - 1)
        return 0.0;
    const double e1 = 0.6065306597126334236038;  // exp(-0.5)
    const double A[5]  = { e1, 1.0 + e1, 1.0 + 2.0 * e1, 1.0 + e1, e1 };
    const double B[5]  = { e1, 1.0 + 2.0 * e1, 2.0 + 2.0 * e1, 1.0 + 2.0 * e1, e1 };
    const double Dk[5] = { -e1, -1.0, 0.0, 1.0, e1 };
    const double s1 = 1.0 + 2.0 * e1;
    const double invS = 1.0 / (s1 * s1 * s1);
    int wi[5], hi5[5], di[5];
    for (int c = 0; c < 5; ++c) {
        wi[c] = refl(w - 2 + c); hi5[c] = refl(h - 2 + c); di[c] = refl(d - 2 + c);
    }
    double gx = 0.0, gy = 0.0, gz = 0.0;
    for (int a = 0; a < 5; ++a) {
        const float* pz = x + (size_t)di[a] * N2;
        for (int b = 0; b < 5; ++b) {
            const float* py = pz + (size_t)hi5[b] * N;
            double rA = 0.0, rB = 0.0, rD = 0.0;
            for (int c = 0; c < 5; ++c) {
                const double v = (double)py[wi[c]];
                rA += A[c] * v; rB += B[c] * v; rD += Dk[c] * v;
            }
            gx += A[a]  * B[b]  * rD;
            gy += A[a]  * Dk[b] * rB;
            gz += Dk[a] * A[b]  * rA;
        }
    }
    gx *= invS; gy *= invS; gz *= invS;
    return sqrt(gx * gx + gy * gy + gz * gz);
}

// ---------------------------------------------------------------------------
// K1: f32 fused Gaussian->Sobel->|grad| with full separable decomposition.
//   per d-offset a: 1D h-reductions rA (A_h), rB (B_h), rD (D_h)  (~12 ops)
//   then 1D d-combos -> P_gx (A_d of rB), P_gy (A_d of rD), P_gz (D_d of rA)
//   P staged in LDS, then 1D w-convs: gx = D_w(Pgx), gy = B_w(Pgy), gz = A_w(Pgz)
// A.v = e1*(s+u+2c)+(u+c); B.v = e1*(s+2(u+c))+(u+2c); D.v = e1*(v4-v0)+(v3-v1)
//   where s=v0+v4, u=v1+v3, c=v2.
// ---------------------------------------------------------------------------
__global__ __launch_bounds__(256) void mag32_kernel(const float* __restrict__ x,
                                                    float* __restrict__ mag,
                                                    uint32_t* __restrict__ cnt) {
    const int w = threadIdx.x;
    const int h = blockIdx.y;
    const int d = blockIdx.z;
    if (w == 0 && h == 0 && d == 0) *cnt = 0;  // reset marked-list counter
    const size_t idx = (size_t)d * N2 + (size_t)h * N + w;

    __shared__ float sPx[N], sPy[N], sPz[N];

    if (d == 0 || d == N - 1 || h == 0 || h == N - 1) {  // whole-block uniform
        mag[idx] = 0.0f;
        return;
    }

    constexpr double E1 = 0.6065306597126334236038;
    const float fe1   = (float)E1;
    const float finvS = (float)(1.0 / ((1.0 + 2.0 * E1) * (1.0 + 2.0 * E1) * (1.0 + 2.0 * E1)));

    int di[5], hi5[5];
#pragma unroll
    for (int c = 0; c < 5; ++c) { di[c] = refl(d - 2 + c); hi5[c] = refl(h - 2 + c); }

    float rA[5], rB[5], rD[5];
#pragma unroll
    for (int a = 0; a < 5; ++a) {
        const float* pz = x + (size_t)di[a] * N2 + w;
        const float v0 = pz[(size_t)hi5[0] * N];
        const float v1 = pz[(size_t)hi5[1] * N];
        const float v2 = pz[(size_t)hi5[2] * N];
        const float v3 = pz[(size_t)hi5[3] * N];
        const float v4 = pz[(size_t)hi5[4] * N];
        const float s = v0 + v4, u = v1 + v3;
        const float m = u + v2, n = s + u;
        rA[a] = fmaf(fe1, fmaf(2.0f, v2, n), m);
        rB[a] = fmaf(fe1, fmaf(2.0f, m, s), fmaf(2.0f, v2, u));
        rD[a] = fmaf(fe1, v4 - v0, v3 - v1);
    }

    float Pgx, Pgy, Pgz;
    {   // A_d over rB
        const float s = rB[0] + rB[4], u = rB[1] + rB[3];
        Pgx = finvS * fmaf(fe1, fmaf(2.0f, rB[2], s + u), u + rB[2]);
    }
    {   // A_d over rD
        const float s = rD[0] + rD[4], u = rD[1] + rD[3];
        Pgy = finvS * fmaf(fe1, fmaf(2.0f, rD[2], s + u), u + rD[2]);
    }
    // D_d over rA
    Pgz = finvS * fmaf(fe1, rA[4] - rA[0], rA[3] - rA[1]);

    sPx[w] = Pgx; sPy[w] = Pgy; sPz[w] = Pgz;
    __syncthreads();

    if (w == 0 || w == N - 1) { mag[idx] = 0.0f; return; }
    const int wm2 = refl(w - 2), wm1 = w - 1, wp1 = w + 1, wp2 = refl(w + 2);

    // gx = D_w(Pgx)
    const float gx = fmaf(fe1, sPx[wp2] - sPx[wm2], sPx[wp1] - sPx[wm1]);
    // gy = B_w(Pgy)
    float gy;
    {
        const float s = sPy[wm2] + sPy[wp2], u = sPy[wm1] + sPy[wp1];
        gy = fmaf(fe1, fmaf(2.0f, u + sPy[w], s), fmaf(2.0f, sPy[w], u));
    }
    // gz = A_w(Pgz)
    float gz;
    {
        const float s = sPz[wm2] + sPz[wp2], u = sPz[wm1] + sPz[wp1];
        gz = fmaf(fe1, fmaf(2.0f, sPz[w], s + u), u + sPz[w]);
    }
    mag[idx] = sqrtf(fmaf(gx, gx, fmaf(gy, gy, gz * gz)));
}

// ---------------------------------------------------------------------------
// K2: NMS + double threshold from f32 mag; mark decision-uncertain voxels.
// flags: 2 = strong, 1 = weak, 0 = none.
// Not-marked implies the f32 decision provably equals the f64 decision.
// ---------------------------------------------------------------------------
__global__ __launch_bounds__(256) void nms_mark_kernel(const float* __restrict__ mag,
                                                       uint8_t* __restrict__ flags,
                                                       uint32_t* __restrict__ cnt,
                                                       uint32_t* __restrict__ list) {
    const int w = threadIdx.x;
    const int h = blockIdx.y;
    const int d = blockIdx.z;
    const size_t idx = (size_t)d * N2 + (size_t)h * N + w;

    uint8_t f = 0;
    if (d > 0 && d < N - 1 && h > 0 && h < N - 1 && w > 0 && w < N - 1) {
        const float m0 = mag[idx];
        const float* p = mag + (size_t)(d - 1) * N2 + (size_t)h * N + w;
        float mn = m0 - p[-N - 1];
        mn = fminf(mn, m0 - p[-N]);
        mn = fminf(mn, m0 - p[-N + 1]);
        mn = fminf(mn, m0 - p[-1]);
        mn = fminf(mn, m0 - p[1]);
        mn = fminf(mn, m0 - p[N - 1]);
        mn = fminf(mn, m0 - p[N]);
        mn = fminf(mn, m0 - p[N + 1]);
        const bool keep = mn > 0.0f;
        if (keep) f = (m0 > 0.2f) ? 2 : ((m0 > 0.1f) ? 1 : 0);
        const bool uncertain = (mn > -EPS) &&
            ((mn <= EPS) || (keep && (fabsf(m0 - 0.2f) < EPS || fabsf(m0 - 0.1f) < EPS)));
        if (uncertain) {
            const uint32_t pos = atomicAdd(cnt, 1u);
            if (pos < CAP) list[pos] = (uint32_t)idx;
        }
    }
    flags[idx] = f;
}

// ---------------------------------------------------------------------------
// K2b: exact-f64 re-decision for marked voxels (voxel + its 8 NMS neighbors).
// ---------------------------------------------------------------------------
__global__ __launch_bounds__(256) void fixup_kernel(const float* __restrict__ x,
                                                    const uint32_t* __restrict__ cnt,
                                                    const uint32_t* __restrict__ list,
                                                    uint8_t* __restrict__ flags) {
    const uint32_t n = min(*cnt, CAP);
    for (uint32_t i = blockIdx.x * blockDim.x + threadIdx.x; i < n;
         i += gridDim.x * blockDim.x) {
        const uint32_t idx = list[i];
        const int w = idx & (N - 1);
        const int h = (idx >> 8) & (N - 1);
        const int d = (int)(idx >> 16);
        const double m0 = mag_f64(x, d, h, w);
        bool keep = true;
        for (int dy = -1; dy <= 1 && keep; ++dy)
            for (int dz = -1; dz <= 1; ++dz) {
                if (dy == 0 && dz == 0) continue;
                if (!(m0 > mag_f64(x, d - 1, h + dy, w + dz))) { keep = false; break; }
            }
        uint8_t f = 0;
        if (keep) f = (m0 > 0.2) ? 2 : ((m0 > 0.1) ? 1 : 0);
        flags[idx] = f;
    }
}

// ---------------------------------------------------------------------------
// K3: single-pass hysteresis: strong, or weak with a 6-connected strong nbr.
// Output int32 0/1 (harness reads d_out as np.int32 for the int8 reference).
// ---------------------------------------------------------------------------
__global__ __launch_bounds__(256) void hyst_kernel(const uint8_t* __restrict__ flags,
                                                   int* __restrict__ out) {
    const int w = threadIdx.x;
    const int h = blockIdx.y;
    const int d = blockIdx.z;
    const size_t idx = (size_t)d * N2 + (size_t)h * N + w;

    const uint8_t f = flags[idx];
    int r = 0;
    if (f == 2) {
        r = 1;
    } else if (f == 1) {  // weak implies interior, so all 6 nbrs in-bounds
        if (flags[idx - N2] == 2 || flags[idx + N2] == 2 ||
            flags[idx - N]  == 2 || flags[idx + N]  == 2 ||
            flags[idx - 1]  == 2 || flags[idx + 1]  == 2)
            r = 1;
    }
    out[idx] = r;
}

extern "C" void kernel_launch(void* const* d_in, const int* in_sizes, int n_in,
                              void* d_out, int out_size, void* d_ws, size_t ws_size,
                              hipStream_t stream) {
    const float* x = (const float*)d_in[0];
    int* out = (int*)d_out;

    // ws layout: [0,64MiB) f32 mag; [64,80MiB) u8 flags; 80MiB: u32 counter;
    //            [80MiB+64B, +16MiB) u32 marked-voxel list
    float*    mag   = (float*)d_ws;
    uint8_t*  flags = (uint8_t*)d_ws + (size_t)N3 * 4;
    uint32_t* cnt   = (uint32_t*)((char*)d_ws + (size_t)N3 * 5);
    uint32_t* list  = (uint32_t*)((char*)d_ws + (size_t)N3 * 5 + 64);

    dim3 block(N, 1, 1);
    dim3 grid(1, N, N);
    mag32_kernel<<<grid, block, 0, stream>>>(x, mag, cnt);
    nms_mark_kernel<<<grid, block, 0, stream>>>(mag, flags, cnt, list);
    fixup_kernel<<<dim3(512), dim3(256), 0, stream>>>(x, cnt, list, flags);
    hyst_kernel<<<grid, block, 0, stream>>>(flags, out);
}

// Round 4
// 136.206 us; speedup vs baseline: 3.4213x; 1.8433x over previous
//
#include <hip/hip_runtime.h>
#include <stdint.h>

#define N  256
#define N2 (N * N)        // 65536
#define N3 (N * N * N)    // 16777216

#define EPS 1e-4f         // decision-uncertainty margin (>> worst-case f32 error ~2e-5)
#define CAP (4u << 20)    // marked-voxel list capacity

// reflect index (jnp.pad mode='reflect'): -1 -> 1, 256 -> 254
__device__ __forceinline__ int refl(int t) {
    t = (t < 0) ? -t : t;
    return (t > N - 1) ? (2 * (N - 1) - t) : t;
}

// ---------------------------------------------------------------------------
// K1: f32 fused Gaussian->Sobel->|grad| with full separable decomposition.
// (verified round 3)
// ---------------------------------------------------------------------------
__global__ __launch_bounds__(256) void mag32_kernel(const float* __restrict__ x,
                                                    float* __restrict__ mag,
                                                    uint32_t* __restrict__ cnt) {
    const int w = threadIdx.x;
    const int h = blockIdx.y;
    const int d = blockIdx.z;
    if (w == 0 && h == 0 && d == 0) *cnt = 0;  // reset marked-list counter
    const size_t idx = (size_t)d * N2 + (size_t)h * N + w;

    __shared__ float sPx[N], sPy[N], sPz[N];

    if (d == 0 || d == N - 1 || h == 0 || h == N - 1) {  // whole-block uniform
        mag[idx] = 0.0f;
        return;
    }

    constexpr double E1 = 0.6065306597126334236038;
    const float fe1   = (float)E1;
    const float finvS = (float)(1.0 / ((1.0 + 2.0 * E1) * (1.0 + 2.0 * E1) * (1.0 + 2.0 * E1)));

    int di[5], hi5[5];
#pragma unroll
    for (int c = 0; c < 5; ++c) { di[c] = refl(d - 2 + c); hi5[c] = refl(h - 2 + c); }

    float rA[5], rB[5], rD[5];
#pragma unroll
    for (int a = 0; a < 5; ++a) {
        const float* pz = x + (size_t)di[a] * N2 + w;
        const float v0 = pz[(size_t)hi5[0] * N];
        const float v1 = pz[(size_t)hi5[1] * N];
        const float v2 = pz[(size_t)hi5[2] * N];
        const float v3 = pz[(size_t)hi5[3] * N];
        const float v4 = pz[(size_t)hi5[4] * N];
        const float s = v0 + v4, u = v1 + v3;
        const float m = u + v2, n = s + u;
        rA[a] = fmaf(fe1, fmaf(2.0f, v2, n), m);
        rB[a] = fmaf(fe1, fmaf(2.0f, m, s), fmaf(2.0f, v2, u));
        rD[a] = fmaf(fe1, v4 - v0, v3 - v1);
    }

    float Pgx, Pgy, Pgz;
    {   // A_d over rB
        const float s = rB[0] + rB[4], u = rB[1] + rB[3];
        Pgx = finvS * fmaf(fe1, fmaf(2.0f, rB[2], s + u), u + rB[2]);
    }
    {   // A_d over rD
        const float s = rD[0] + rD[4], u = rD[1] + rD[3];
        Pgy = finvS * fmaf(fe1, fmaf(2.0f, rD[2], s + u), u + rD[2]);
    }
    // D_d over rA
    Pgz = finvS * fmaf(fe1, rA[4] - rA[0], rA[3] - rA[1]);

    sPx[w] = Pgx; sPy[w] = Pgy; sPz[w] = Pgz;
    __syncthreads();

    if (w == 0 || w == N - 1) { mag[idx] = 0.0f; return; }
    const int wm2 = refl(w - 2), wm1 = w - 1, wp1 = w + 1, wp2 = refl(w + 2);

    const float gx = fmaf(fe1, sPx[wp2] - sPx[wm2], sPx[wp1] - sPx[wm1]);
    float gy;
    {
        const float s = sPy[wm2] + sPy[wp2], u = sPy[wm1] + sPy[wp1];
        gy = fmaf(fe1, fmaf(2.0f, u + sPy[w], s), fmaf(2.0f, sPy[w], u));
    }
    float gz;
    {
        const float s = sPz[wm2] + sPz[wp2], u = sPz[wm1] + sPz[wp1];
        gz = fmaf(fe1, fmaf(2.0f, sPz[w], s + u), u + sPz[w]);
    }
    mag[idx] = sqrtf(fmaf(gx, gx, fmaf(gy, gy, gz * gz)));
}

// ---------------------------------------------------------------------------
// K2: NMS + double threshold from f32 mag; mark decision-uncertain voxels.
// (verified round 3)
// ---------------------------------------------------------------------------
__global__ __launch_bounds__(256) void nms_mark_kernel(const float* __restrict__ mag,
                                                       uint8_t* __restrict__ flags,
                                                       uint32_t* __restrict__ cnt,
                                                       uint32_t* __restrict__ list) {
    const int w = threadIdx.x;
    const int h = blockIdx.y;
    const int d = blockIdx.z;
    const size_t idx = (size_t)d * N2 + (size_t)h * N + w;

    uint8_t f = 0;
    if (d > 0 && d < N - 1 && h > 0 && h < N - 1 && w > 0 && w < N - 1) {
        const float m0 = mag[idx];
        const float* p = mag + (size_t)(d - 1) * N2 + (size_t)h * N + w;
        float mn = m0 - p[-N - 1];
        mn = fminf(mn, m0 - p[-N]);
        mn = fminf(mn, m0 - p[-N + 1]);
        mn = fminf(mn, m0 - p[-1]);
        mn = fminf(mn, m0 - p[1]);
        mn = fminf(mn, m0 - p[N - 1]);
        mn = fminf(mn, m0 - p[N]);
        mn = fminf(mn, m0 - p[N + 1]);
        const bool keep = mn > 0.0f;
        if (keep) f = (m0 > 0.2f) ? 2 : ((m0 > 0.1f) ? 1 : 0);
        const bool uncertain = (mn > -EPS) &&
            ((mn <= EPS) || (keep && (fabsf(m0 - 0.2f) < EPS || fabsf(m0 - 0.1f) < EPS)));
        if (uncertain) {
            const uint32_t pos = atomicAdd(cnt, 1u);
            if (pos < CAP) list[pos] = (uint32_t)idx;
        }
    }
    flags[idx] = f;
}

// ---------------------------------------------------------------------------
// K2b: exact-f64 re-decision, one marked voxel per WAVEFRONT.
// Lane = eval*5 + a: eval 0 = center, evals 1..8 = the 8 NMS neighbors
// (d-1, h+dy, w+dz); a = d-axis tap. Each lane computes its (eval, a)
// partial of the separable f64 composite stencil (25 loads, b/c loops),
// 5-lane shfl_down tree -> per-eval (gx,gy,gz), leader computes mag,
// shfl-broadcast gathers 9 mags, lane 0 decides and stores the flag.
// f64 summation-order differs from the one-thread version only at ~1e-16
// relative, far below any decision margin that matters (round-2 evidence).
// ---------------------------------------------------------------------------
__global__ __launch_bounds__(256) void fixup_wave_kernel(const float* __restrict__ x,
                                                         const uint32_t* __restrict__ cnt,
                                                         const uint32_t* __restrict__ list,
                                                         uint8_t* __restrict__ flags) {
    const uint32_t n = min(*cnt, CAP);
    const int lane = threadIdx.x & 63;
    const uint32_t wave = (blockIdx.x * blockDim.x + threadIdx.x) >> 6;
    const uint32_t nwaves = (gridDim.x * blockDim.x) >> 6;

    // eval 0 = center; 1..8 = _NMS_DIRS (dx=-1 plane)
    const int dy_t[9] = { 0, -1, -1, -1,  0, 0,  1, 1, 1 };
    const int dz_t[9] = { 0, -1,  0,  1, -1, 1, -1, 0, 1 };

    const int e_raw = lane / 5;            // 0..12
    const int a     = lane - e_raw * 5;    // 0..4
    const bool lane_valid = (e_raw < 9);
    const int e = lane_valid ? e_raw : 0;

    const double e1 = 0.6065306597126334236038;  // exp(-0.5)
    const double A[5]  = { e1, 1.0 + e1, 1.0 + 2.0 * e1, 1.0 + e1, e1 };
    const double B[5]  = { e1, 1.0 + 2.0 * e1, 2.0 + 2.0 * e1, 1.0 + 2.0 * e1, e1 };
    const double Dk[5] = { -e1, -1.0, 0.0, 1.0, e1 };
    const double s1 = 1.0 + 2.0 * e1;
    const double invS = 1.0 / (s1 * s1 * s1);

    for (uint32_t v = wave; v < n; v += nwaves) {
        const uint32_t idx = list[v];
        const int w0 = idx & (N - 1);
        const int h0 = (idx >> 8) & (N - 1);
        const int d0 = (int)(idx >> 16);

        const int pd = (e == 0) ? d0 : d0 - 1;
        const int ph = h0 + dy_t[e];
        const int pw = w0 + dz_t[e];
        const bool border = !lane_valid ||
            (pd == 0 || pd == N - 1 || ph == 0 || ph == N - 1 || pw == 0 || pw == N - 1);

        double pgx = 0.0, pgy = 0.0, pgz = 0.0;
        if (!border) {
            const float* pz = x + (size_t)refl(pd - 2 + a) * N2;
            int wi[5];
#pragma unroll
            for (int c = 0; c < 5; ++c) wi[c] = refl(pw - 2 + c);
#pragma unroll
            for (int b = 0; b < 5; ++b) {
                const float* py = pz + (size_t)refl(ph - 2 + b) * N;
                double rA = 0.0, rB = 0.0, rD = 0.0;
#pragma unroll
                for (int c = 0; c < 5; ++c) {
                    const double vv = (double)py[wi[c]];
                    rA += A[c] * vv; rB += B[c] * vv; rD += Dk[c] * vv;
                }
                pgx += A[a]  * B[b]  * rD;
                pgy += A[a]  * Dk[b] * rB;
                pgz += Dk[a] * A[b]  * rA;
            }
        }

        // reduce the 5 a-lanes of each eval into the leader (a == 0)
        double sgx = pgx, sgy = pgy, sgz = pgz;
#pragma unroll
        for (int off = 1; off < 5; ++off) {
            sgx += __shfl_down(pgx, off);
            sgy += __shfl_down(pgy, off);
            sgz += __shfl_down(pgz, off);
        }
        double m = 0.0;
        if (!border && a == 0) {
            sgx *= invS; sgy *= invS; sgz *= invS;
            m = sqrt(sgx * sgx + sgy * sgy + sgz * sgz);
        }

        // gather the 9 mags; decide on lane 0
        const double m0 = __shfl(m, 0);
        bool keep = true;
#pragma unroll
        for (int e2 = 1; e2 < 9; ++e2) {
            const double nb = __shfl(m, 5 * e2);
            keep = keep && (m0 > nb);
        }
        if (lane == 0) {
            uint8_t f = 0;
            if (keep) f = (m0 > 0.2) ? 2 : ((m0 > 0.1) ? 1 : 0);
            flags[idx] = f;
        }
    }
}

// ---------------------------------------------------------------------------
// K3: hysteresis, 4 voxels per thread. uchar4 center load, int4 store,
// lazy neighbor byte loads only when weak (weak implies interior).
// ---------------------------------------------------------------------------
__global__ __launch_bounds__(256) void hyst4_kernel(const uint8_t* __restrict__ flags,
                                                    int* __restrict__ out) {
    const int w4 = threadIdx.x * 4;                    // 0..252, x-dim = 64
    const int h  = blockIdx.y * 4 + threadIdx.y;       // y-dim = 4
    const int d  = blockIdx.z;
    const size_t base = (size_t)d * N2 + (size_t)h * N + w4;

    const uchar4 f4 = *(const uchar4*)(flags + base);
    const uint8_t f[4] = { f4.x, f4.y, f4.z, f4.w };
    int r[4];
#pragma unroll
    for (int i = 0; i < 4; ++i) {
        int rr = 0;
        if (f[i] == 2) {
            rr = 1;
        } else if (f[i] == 1) {  // weak implies interior: all 6 nbrs in-bounds
            const size_t idx = base + i;
            if (flags[idx - N2] == 2 || flags[idx + N2] == 2 ||
                flags[idx - N]  == 2 || flags[idx + N]  == 2 ||
                flags[idx - 1]  == 2 || flags[idx + 1]  == 2)
                rr = 1;
        }
        r[i] = rr;
    }
    *(int4*)(out + base) = make_int4(r[0], r[1], r[2], r[3]);
}

extern "C" void kernel_launch(void* const* d_in, const int* in_sizes, int n_in,
                              void* d_out, int out_size, void* d_ws, size_t ws_size,
                              hipStream_t stream) {
    const float* x = (const float*)d_in[0];
    int* out = (int*)d_out;

    // ws layout: [0,64MiB) f32 mag; [64,80MiB) u8 flags; 80MiB: u32 counter;
    //            [80MiB+64B, +16MiB) u32 marked-voxel list
    float*    mag   = (float*)d_ws;
    uint8_t*  flags = (uint8_t*)d_ws + (size_t)N3 * 4;
    uint32_t* cnt   = (uint32_t*)((char*)d_ws + (size_t)N3 * 5);
    uint32_t* list  = (uint32_t*)((char*)d_ws + (size_t)N3 * 5 + 64);

    dim3 block(N, 1, 1);
    dim3 grid(1, N, N);
    mag32_kernel<<<grid, block, 0, stream>>>(x, mag, cnt);
    nms_mark_kernel<<<grid, block, 0, stream>>>(mag, flags, cnt, list);
    fixup_wave_kernel<<<dim3(1024), dim3(256), 0, stream>>>(x, cnt, list, flags);
    hyst4_kernel<<<dim3(1, 64, N), dim3(64, 4, 1), 0, stream>>>(flags, out);
}

// Round 5
// 102.279 us; speedup vs baseline: 4.5561x; 1.3317x over previous
//
#include <hip/hip_runtime.h>
#include <stdint.h>

#define N  256
#define N2 (N * N)        // 65536
#define N3 (N * N * N)    // 16777216

#define EPS 1e-4f         // decision-uncertainty margin (>> worst-case f32 error ~2e-5)
#define CAP (4u << 20)    // marked-voxel list capacity
#define DCHUNK 32
#define NCHUNK (N / DCHUNK)  // 8

// reflect index (jnp.pad mode='reflect'): -1 -> 1, 256 -> 254
__device__ __forceinline__ int refl(int t) {
    t = (t < 0) ? -t : t;
    return (t > N - 1) ? (2 * (N - 1) - t) : t;
}

// ---------------------------------------------------------------------------
// K1: f32 fused Gaussian->Sobel->|grad|, rolling-window march along d.
// Block = one (h, all w) row x one 32-deep d-chunk. Per d-step: ONE new
// plane's h-reduction (5 loads + 12 FLOPs), register window of last 5,
// d-combine -> P, LDS (double-buffered) -> w-convs -> mag.
// Expressions identical to the round-3 verified kernel.
// ---------------------------------------------------------------------------
__global__ __launch_bounds__(256) void mag_roll_kernel(const float* __restrict__ x,
                                                       float* __restrict__ mag,
                                                       uint32_t* __restrict__ cnt) {
    const int w  = threadIdx.x;
    const int lb = blockIdx.y;
    const int h  = ((lb & 7) << 5) | (lb >> 3);  // XCD-contiguous h ranges
    const int dlo = blockIdx.z * DCHUNK;
    if (w == 0 && lb == 0 && blockIdx.z == 0) *cnt = 0;

    const size_t rowbase = (size_t)h * N + w;

    if (h == 0 || h == N - 1) {  // zero border rows for the whole chunk
        for (int j = 0; j < DCHUNK; ++j)
            mag[(size_t)(dlo + j) * N2 + rowbase] = 0.0f;
        return;
    }

    constexpr double E1 = 0.6065306597126334236038;  // exp(-0.5)
    const float fe1   = (float)E1;
    const float finvS = (float)(1.0 / ((1.0 + 2.0 * E1) * (1.0 + 2.0 * E1) * (1.0 + 2.0 * E1)));

    __shared__ float sP[2][3][N];

    int hoff[5];
#pragma unroll
    for (int c = 0; c < 5; ++c) hoff[c] = refl(h - 2 + c) * N;

    float rA[5], rB[5], rD[5];

    // h-reduction of plane p into window slot k
    auto hred = [&](int p, int k) {
        const float* pz = x + (size_t)refl(p) * N2 + w;
        const float v0 = pz[hoff[0]];
        const float v1 = pz[hoff[1]];
        const float v2 = pz[hoff[2]];
        const float v3 = pz[hoff[3]];
        const float v4 = pz[hoff[4]];
        const float s = v0 + v4, u = v1 + v3;
        const float m = u + v2, n = s + u;
        rA[k] = fmaf(fe1, fmaf(2.0f, v2, n), m);
        rB[k] = fmaf(fe1, fmaf(2.0f, m, s), fmaf(2.0f, v2, u));
        rD[k] = fmaf(fe1, v4 - v0, v3 - v1);
    };

    // prologue: planes dlo-2..dlo+1 -> slots 0..3
    hred(dlo - 2, 0);
    hred(dlo - 1, 1);
    hred(dlo,     2);
    hred(dlo + 1, 3);

    const int wm2 = refl(w - 2), wm1 = refl(w - 1), wp1 = refl(w + 1), wp2 = refl(w + 2);
    const bool w_int = (w > 0 && w < N - 1);

#pragma unroll 4
    for (int j = 0; j < DCHUNK; ++j) {
        const int d = dlo + j;
        hred(d + 2, 4);

        float Pgx, Pgy, Pgz;
        {   // A_d over rB
            const float s = rB[0] + rB[4], u = rB[1] + rB[3];
            Pgx = finvS * fmaf(fe1, fmaf(2.0f, rB[2], s + u), u + rB[2]);
        }
        {   // A_d over rD
            const float s = rD[0] + rD[4], u = rD[1] + rD[3];
            Pgy = finvS * fmaf(fe1, fmaf(2.0f, rD[2], s + u), u + rD[2]);
        }
        // D_d over rA
        Pgz = finvS * fmaf(fe1, rA[4] - rA[0], rA[3] - rA[1]);

        const int b = j & 1;
        sP[b][0][w] = Pgx; sP[b][1][w] = Pgy; sP[b][2][w] = Pgz;
        __syncthreads();

        float m = 0.0f;
        if (w_int && d > 0 && d < N - 1) {
            const float gx = fmaf(fe1, sP[b][0][wp2] - sP[b][0][wm2],
                                       sP[b][0][wp1] - sP[b][0][wm1]);
            float gy;
            {
                const float s = sP[b][1][wm2] + sP[b][1][wp2];
                const float u = sP[b][1][wm1] + sP[b][1][wp1];
                gy = fmaf(fe1, fmaf(2.0f, u + sP[b][1][w], s), fmaf(2.0f, sP[b][1][w], u));
            }
            float gz;
            {
                const float s = sP[b][2][wm2] + sP[b][2][wp2];
                const float u = sP[b][2][wm1] + sP[b][2][wp1];
                gz = fmaf(fe1, fmaf(2.0f, sP[b][2][w], s + u), u + sP[b][2][w]);
            }
            m = sqrtf(fmaf(gx, gx, fmaf(gy, gy, gz * gz)));
        }
        mag[(size_t)d * N2 + rowbase] = m;

        // shift window
        rA[0] = rA[1]; rA[1] = rA[2]; rA[2] = rA[3]; rA[3] = rA[4];
        rB[0] = rB[1]; rB[1] = rB[2]; rB[2] = rB[3]; rB[3] = rB[4];
        rD[0] = rD[1]; rD[1] = rD[2]; rD[2] = rD[3]; rD[3] = rD[4];
    }
}

// ---------------------------------------------------------------------------
// K2: NMS + double threshold from f32 mag; mark decision-uncertain voxels.
// (verified round 3)
// ---------------------------------------------------------------------------
__global__ __launch_bounds__(256) void nms_mark_kernel(const float* __restrict__ mag,
                                                       uint8_t* __restrict__ flags,
                                                       uint32_t* __restrict__ cnt,
                                                       uint32_t* __restrict__ list) {
    const int w = threadIdx.x;
    const int h = blockIdx.y;
    const int d = blockIdx.z;
    const size_t idx = (size_t)d * N2 + (size_t)h * N + w;

    uint8_t f = 0;
    if (d > 0 && d < N - 1 && h > 0 && h < N - 1 && w > 0 && w < N - 1) {
        const float m0 = mag[idx];
        const float* p = mag + (size_t)(d - 1) * N2 + (size_t)h * N + w;
        float mn = m0 - p[-N - 1];
        mn = fminf(mn, m0 - p[-N]);
        mn = fminf(mn, m0 - p[-N + 1]);
        mn = fminf(mn, m0 - p[-1]);
        mn = fminf(mn, m0 - p[1]);
        mn = fminf(mn, m0 - p[N - 1]);
        mn = fminf(mn, m0 - p[N]);
        mn = fminf(mn, m0 - p[N + 1]);
        const bool keep = mn > 0.0f;
        if (keep) f = (m0 > 0.2f) ? 2 : ((m0 > 0.1f) ? 1 : 0);
        const bool uncertain = (mn > -EPS) &&
            ((mn <= EPS) || (keep && (fabsf(m0 - 0.2f) < EPS || fabsf(m0 - 0.1f) < EPS)));
        if (uncertain) {
            const uint32_t pos = atomicAdd(cnt, 1u);
            if (pos < CAP) list[pos] = (uint32_t)idx;
        }
    }
    flags[idx] = f;
}

// ---------------------------------------------------------------------------
// K2b: exact-f64 re-decision, one marked voxel per WAVEFRONT (round-4 verified).
// ---------------------------------------------------------------------------
__global__ __launch_bounds__(256) void fixup_wave_kernel(const float* __restrict__ x,
                                                         const uint32_t* __restrict__ cnt,
                                                         const uint32_t* __restrict__ list,
                                                         uint8_t* __restrict__ flags) {
    const uint32_t n = min(*cnt, CAP);
    const int lane = threadIdx.x & 63;
    const uint32_t wave = (blockIdx.x * blockDim.x + threadIdx.x) >> 6;
    const uint32_t nwaves = (gridDim.x * blockDim.x) >> 6;

    const int dy_t[9] = { 0, -1, -1, -1,  0, 0,  1, 1, 1 };
    const int dz_t[9] = { 0, -1,  0,  1, -1, 1, -1, 0, 1 };

    const int e_raw = lane / 5;            // 0..12
    const int a     = lane - e_raw * 5;    // 0..4
    const bool lane_valid = (e_raw < 9);
    const int e = lane_valid ? e_raw : 0;

    const double e1 = 0.6065306597126334236038;  // exp(-0.5)
    const double A[5]  = { e1, 1.0 + e1, 1.0 + 2.0 * e1, 1.0 + e1, e1 };
    const double B[5]  = { e1, 1.0 + 2.0 * e1, 2.0 + 2.0 * e1, 1.0 + 2.0 * e1, e1 };
    const double Dk[5] = { -e1, -1.0, 0.0, 1.0, e1 };
    const double s1 = 1.0 + 2.0 * e1;
    const double invS = 1.0 / (s1 * s1 * s1);

    for (uint32_t v = wave; v < n; v += nwaves) {
        const uint32_t idx = list[v];
        const int w0 = idx & (N - 1);
        const int h0 = (idx >> 8) & (N - 1);
        const int d0 = (int)(idx >> 16);

        const int pd = (e == 0) ? d0 : d0 - 1;
        const int ph = h0 + dy_t[e];
        const int pw = w0 + dz_t[e];
        const bool border = !lane_valid ||
            (pd == 0 || pd == N - 1 || ph == 0 || ph == N - 1 || pw == 0 || pw == N - 1);

        double pgx = 0.0, pgy = 0.0, pgz = 0.0;
        if (!border) {
            const float* pz = x + (size_t)refl(pd - 2 + a) * N2;
            int wi[5];
#pragma unroll
            for (int c = 0; c < 5; ++c) wi[c] = refl(pw - 2 + c);
#pragma unroll
            for (int b = 0; b < 5; ++b) {
                const float* py = pz + (size_t)refl(ph - 2 + b) * N;
                double rA = 0.0, rB = 0.0, rD = 0.0;
#pragma unroll
                for (int c = 0; c < 5; ++c) {
                    const double vv = (double)py[wi[c]];
                    rA += A[c] * vv; rB += B[c] * vv; rD += Dk[c] * vv;
                }
                pgx += A[a]  * B[b]  * rD;
                pgy += A[a]  * Dk[b] * rB;
                pgz += Dk[a] * A[b]  * rA;
            }
        }

        double sgx = pgx, sgy = pgy, sgz = pgz;
#pragma unroll
        for (int off = 1; off < 5; ++off) {
            sgx += __shfl_down(pgx, off);
            sgy += __shfl_down(pgy, off);
            sgz += __shfl_down(pgz, off);
        }
        double m = 0.0;
        if (!border && a == 0) {
            sgx *= invS; sgy *= invS; sgz *= invS;
            m = sqrt(sgx * sgx + sgy * sgy + sgz * sgz);
        }

        const double m0 = __shfl(m, 0);
        bool keep = true;
#pragma unroll
        for (int e2 = 1; e2 < 9; ++e2) {
            const double nb = __shfl(m, 5 * e2);
            keep = keep && (m0 > nb);
        }
        if (lane == 0) {
            uint8_t f = 0;
            if (keep) f = (m0 > 0.2) ? 2 : ((m0 > 0.1) ? 1 : 0);
            flags[idx] = f;
        }
    }
}

// ---------------------------------------------------------------------------
// K3: hysteresis, 4 voxels per thread (round-4 verified).
// ---------------------------------------------------------------------------
__global__ __launch_bounds__(256) void hyst4_kernel(const uint8_t* __restrict__ flags,
                                                    int* __restrict__ out) {
    const int w4 = threadIdx.x * 4;                    // 0..252, x-dim = 64
    const int h  = blockIdx.y * 4 + threadIdx.y;       // y-dim = 4
    const int d  = blockIdx.z;
    const size_t base = (size_t)d * N2 + (size_t)h * N + w4;

    const uchar4 f4 = *(const uchar4*)(flags + base);
    const uint8_t f[4] = { f4.x, f4.y, f4.z, f4.w };
    int r[4];
#pragma unroll
    for (int i = 0; i < 4; ++i) {
        int rr = 0;
        if (f[i] == 2) {
            rr = 1;
        } else if (f[i] == 1) {  // weak implies interior: all 6 nbrs in-bounds
            const size_t idx = base + i;
            if (flags[idx - N2] == 2 || flags[idx + N2] == 2 ||
                flags[idx - N]  == 2 || flags[idx + N]  == 2 ||
                flags[idx - 1]  == 2 || flags[idx + 1]  == 2)
                rr = 1;
        }
        r[i] = rr;
    }
    *(int4*)(out + base) = make_int4(r[0], r[1], r[2], r[3]);
}

extern "C" void kernel_launch(void* const* d_in, const int* in_sizes, int n_in,
                              void* d_out, int out_size, void* d_ws, size_t ws_size,
                              hipStream_t stream) {
    const float* x = (const float*)d_in[0];
    int* out = (int*)d_out;

    // ws layout: [0,64MiB) f32 mag; [64,80MiB) u8 flags; 80MiB: u32 counter;
    //            [80MiB+64B, +16MiB) u32 marked-voxel list
    float*    mag   = (float*)d_ws;
    uint8_t*  flags = (uint8_t*)d_ws + (size_t)N3 * 4;
    uint32_t* cnt   = (uint32_t*)((char*)d_ws + (size_t)N3 * 5);
    uint32_t* list  = (uint32_t*)((char*)d_ws + (size_t)N3 * 5 + 64);

    mag_roll_kernel<<<dim3(1, N, NCHUNK), dim3(N, 1, 1), 0, stream>>>(x, mag, cnt);
    nms_mark_kernel<<<dim3(1, N, N), dim3(N, 1, 1), 0, stream>>>(mag, flags, cnt, list);
    fixup_wave_kernel<<<dim3(1024), dim3(256), 0, stream>>>(x, cnt, list, flags);
    hyst4_kernel<<<dim3(1, 64, N), dim3(64, 4, 1), 0, stream>>>(flags, out);
}